// Round 1
// baseline (492.422 us; speedup 1.0000x reference)
//
#include <hip/hip_runtime.h>
#include <hip/hip_fp16.h>

// ---------------------------------------------------------------------------
// ClassificationKNNLoss on MI355X.
// Fused design: never materialize the 8192x8192 distance matrix.
//   k_prep : norms + bf16 convert with granule-XOR swizzle (for LDS bank-free reads)
//   k_samp : MFMA GEMM over 1024 sampled cols/row -> f16 distances (subset)
//   k_tau  : per-row 16th-smallest of samples = conservative threshold tau
//   k_main : full GEMM; per value: d, exp(-d)->denom, d16<=tau -> append passer
//   k_fin  : per-row top-16 of passers, label match, loss reduction
// ---------------------------------------------------------------------------

typedef __attribute__((ext_vector_type(8))) short s8v;    // 8 x bf16 (4 VGPR)
typedef __attribute__((ext_vector_type(4))) float f32x4;  // MFMA acc

#define NROW 8192
#define NK   256
#define SAMPN 1024
#define CAP  512

// ws byte offsets
#define OFF_CNT  0                         // u32[8192]
#define OFF_DEN  32768                     // f32[8192]
#define OFF_NRM  65536                     // f32[8192]
#define OFF_TAU  98304                     // u32[8192]
#define OFF_XB   131072                    // u16[8192*256] swizzled bf16 (4.19MB)
#define OFF_SAMP (OFF_XB + NROW * NK * 2)  // u16[8192*1024] samples, reused as u32[8192*512] passers

__device__ __forceinline__ unsigned short f2bf(float f) {
  unsigned u = __float_as_uint(f);
  return (unsigned short)((u + 0x7FFFu + ((u >> 16) & 1u)) >> 16);  // RNE
}

// identical expression in k_samp and k_main -> bitwise-equal d for sampled cols
__device__ __forceinline__ float distf(float acc, float s) {
  return sqrtf(fmaxf(fmaf(acc, -2.0f, s), 0.0f));
}

__device__ __forceinline__ void gld16(const void* g, void* l) {
  __builtin_amdgcn_global_load_lds(
      (const __attribute__((address_space(1))) unsigned int*)g,
      (__attribute__((address_space(3))) unsigned int*)l, 16, 0, 0);
}

__device__ __forceinline__ unsigned umin32(unsigned a, unsigned b) { return a < b ? a : b; }

// ---------------------------------------------------------------- k_prep ----
// xb[(r,k)] stored at u16 index r*256 + ((k>>3) ^ (r&7))*8 + (k&7)
__global__ __launch_bounds__(256) void k_prep(const float* __restrict__ x,
                                              unsigned short* __restrict__ xb,
                                              float* __restrict__ nrm) {
  const int w = threadIdx.x >> 6, l = threadIdx.x & 63;
  const int r = blockIdx.x * 4 + w;
  const float4 xv = *reinterpret_cast<const float4*>(x + r * NK + l * 4);
  float ns = xv.x * xv.x + xv.y * xv.y + xv.z * xv.z + xv.w * xv.w;
  ns += __shfl_xor(ns, 1);  ns += __shfl_xor(ns, 2);  ns += __shfl_xor(ns, 4);
  ns += __shfl_xor(ns, 8);  ns += __shfl_xor(ns, 16); ns += __shfl_xor(ns, 32);
  if (l == 0) nrm[r] = ns;
  ushort4 bv;
  bv.x = f2bf(xv.x); bv.y = f2bf(xv.y); bv.z = f2bf(xv.z); bv.w = f2bf(xv.w);
  const int gs = (l >> 1) ^ (r & 7);  // elements k=4l..4l+3 live in granule l>>1
  *reinterpret_cast<ushort4*>(xb + r * NK + gs * 8 + (l & 1) * 4) = bv;
}

// ---------------------------------------------------------------- k_samp ----
// Sampled col s (0..1023) -> global row j(s) = 8s + (s&7)  (phase drifts so
// (j&7) == (s&7) keeps the swizzle active).  Writes f16 d to samp[row][s].
__global__ __launch_bounds__(256) void k_samp(const unsigned short* __restrict__ xb,
                                              const float* __restrict__ nrm,
                                              unsigned short* __restrict__ samp) {
  __shared__ __align__(16) unsigned short Bl[2][64 * NK];  // 2 x 32KB
  __shared__ float ncs[2][64];
  const int tid = threadIdx.x;
  const int w = tid >> 6, l = tid & 63, l15 = l & 15, l4 = l >> 4;
  const int rb = blockIdx.x >> 2, ss = blockIdx.x & 3;
  const int rowbase = rb * 128 + (w >> 1) * 64;
  const int wcol = (w & 1) * 32;
  const int sbase = ss * 256;

  s8v A[4][8];
  #pragma unroll
  for (int rf = 0; rf < 4; ++rf) {
    const int rr = rowbase + rf * 16 + l15;
    #pragma unroll
    for (int kf = 0; kf < 8; ++kf) {
      const int g = ((kf << 2) | l4) ^ (rr & 7);
      A[rf][kf] = *reinterpret_cast<const s8v*>(xb + rr * NK + g * 8);
    }
  }
  float nr[4][4];
  #pragma unroll
  for (int rf = 0; rf < 4; ++rf)
    #pragma unroll
    for (int q = 0; q < 4; ++q) nr[rf][q] = nrm[rowbase + rf * 16 + l4 * 4 + q];

  auto stage = [&](int buf, int t) {
    #pragma unroll
    for (int jj = 0; jj < 8; ++jj) {
      const int unit = jj * 256 + tid;
      const int sc = unit >> 5, gsl = unit & 31;
      const int si = sbase + t * 64 + sc;
      const int jrow = si * 8 + (si & 7);
      gld16(xb + jrow * NK + gsl * 8, &Bl[buf][(jj * 256 + w * 64) * 8]);
    }
    if (tid < 64) {
      const int si = sbase + t * 64 + tid;
      ncs[buf][tid] = nrm[si * 8 + (si & 7)];
    }
  };

  stage(0, 0);
  for (int t = 0; t < 4; ++t) {
    const int cur = t & 1;
    __syncthreads();
    if (t + 1 < 4) stage(cur ^ 1, t + 1);
    f32x4 acc[4][2];
    #pragma unroll
    for (int rf = 0; rf < 4; ++rf) {
      f32x4 z = {0.f, 0.f, 0.f, 0.f};
      acc[rf][0] = z; acc[rf][1] = z;
    }
    #pragma unroll
    for (int kf = 0; kf < 8; ++kf) {
      const int gs = ((kf << 2) | l4) ^ (l15 & 7);
      const s8v b0 = *reinterpret_cast<const s8v*>(&Bl[cur][(wcol + l15) * NK + gs * 8]);
      const s8v b1 = *reinterpret_cast<const s8v*>(&Bl[cur][(wcol + 16 + l15) * NK + gs * 8]);
      #pragma unroll
      for (int rf = 0; rf < 4; ++rf) {
        acc[rf][0] = __builtin_amdgcn_mfma_f32_16x16x32_bf16(A[rf][kf], b0, acc[rf][0], 0, 0, 0);
        acc[rf][1] = __builtin_amdgcn_mfma_f32_16x16x32_bf16(A[rf][kf], b1, acc[rf][1], 0, 0, 0);
      }
    }
    #pragma unroll
    for (int rf = 0; rf < 4; ++rf)
      #pragma unroll
      for (int cf = 0; cf < 2; ++cf) {
        const int scol = sbase + t * 64 + wcol + cf * 16 + l15;
        const int jcol = scol * 8 + (scol & 7);
        const float nc = ncs[cur][wcol + cf * 16 + l15];
        #pragma unroll
        for (int q = 0; q < 4; ++q) {
          const int rowg = rowbase + rf * 16 + l4 * 4 + q;
          const float dd = distf(acc[rf][cf][q], nr[rf][q] + nc);
          unsigned short d16 = __half_as_ushort(__float2half(dd));
          if (jcol == rowg) d16 = 0xFFFFu;  // exclude self from the sample
          samp[rowg * SAMPN + scol] = d16;
        }
      }
  }
}

// ----------------------------------------------------------------- k_tau ----
__global__ __launch_bounds__(256) void k_tau(const unsigned short* __restrict__ samp,
                                             unsigned* __restrict__ tauk) {
  const int w = threadIdx.x >> 6, l = threadIdx.x & 63;
  const int r = blockIdx.x * 4 + w;
  const uint4* sp = reinterpret_cast<const uint4*>(samp + r * SAMPN + l * 16);
  const uint4 pa = sp[0], pb = sp[1];
  unsigned v[16];
  v[0] = pa.x & 0xFFFFu;  v[1] = pa.x >> 16;  v[2] = pa.y & 0xFFFFu;  v[3] = pa.y >> 16;
  v[4] = pa.z & 0xFFFFu;  v[5] = pa.z >> 16;  v[6] = pa.w & 0xFFFFu;  v[7] = pa.w >> 16;
  v[8] = pb.x & 0xFFFFu;  v[9] = pb.x >> 16;  v[10] = pb.y & 0xFFFFu; v[11] = pb.y >> 16;
  v[12] = pb.z & 0xFFFFu; v[13] = pb.z >> 16; v[14] = pb.w & 0xFFFFu; v[15] = pb.w >> 16;
  unsigned m = 0;
  for (int pp = 0; pp < 16; ++pp) {  // 16 min-pops; the 16th popped value = tau
    unsigned lm = v[0];
    #pragma unroll
    for (int j = 1; j < 16; ++j) lm = umin32(lm, v[j]);
    m = lm;
    m = umin32(m, __shfl_xor(m, 1));  m = umin32(m, __shfl_xor(m, 2));
    m = umin32(m, __shfl_xor(m, 4));  m = umin32(m, __shfl_xor(m, 8));
    m = umin32(m, __shfl_xor(m, 16)); m = umin32(m, __shfl_xor(m, 32));
    const unsigned long long bal = __ballot(lm == m);
    const int owner = (int)__ffsll(bal) - 1;
    if (l == owner) {
      bool f = false;
      #pragma unroll
      for (int j = 0; j < 16; ++j)
        if (!f && v[j] == m) { v[j] = 0xFFFFFFFFu; f = true; }
    }
  }
  if (l == 0) tauk[r] = m;
}

// ---------------------------------------------------------------- k_main ----
__global__ __launch_bounds__(256) void k_main(const unsigned short* __restrict__ xb,
                                              const float* __restrict__ nrm,
                                              const unsigned* __restrict__ tauk,
                                              float* __restrict__ denom,
                                              unsigned* __restrict__ cnt,
                                              unsigned* __restrict__ pass) {
  __shared__ __align__(16) unsigned short Bl[2][64 * NK];  // 2 x 32KB double buffer
  __shared__ float ncs[2][64];
  const int tid = threadIdx.x;
  const int w = tid >> 6, l = tid & 63, l15 = l & 15, l4 = l >> 4;
  const int rb = blockIdx.x >> 3, cs = blockIdx.x & 7;
  const int rowbase = rb * 128 + (w >> 1) * 64;
  const int wcol = (w & 1) * 32;
  const int colslice = cs * 1024;

  s8v A[4][8];  // 64 rows x K=256 in registers, reused across all 16 col-tiles
  #pragma unroll
  for (int rf = 0; rf < 4; ++rf) {
    const int rr = rowbase + rf * 16 + l15;
    #pragma unroll
    for (int kf = 0; kf < 8; ++kf) {
      const int g = ((kf << 2) | l4) ^ (rr & 7);
      A[rf][kf] = *reinterpret_cast<const s8v*>(xb + rr * NK + g * 8);
    }
  }
  float nr[4][4]; unsigned tk[4][4];
  #pragma unroll
  for (int rf = 0; rf < 4; ++rf)
    #pragma unroll
    for (int q = 0; q < 4; ++q) {
      const int rowg = rowbase + rf * 16 + l4 * 4 + q;
      nr[rf][q] = nrm[rowg];
      tk[rf][q] = tauk[rowg];
    }
  float dn[4][4] = {};

  auto stage = [&](int buf, int t) {
    // tile is contiguous in (pre-swizzled) xb: pure linear 32KB copy
    const unsigned short* src = xb + (colslice + t * 64) * NK;
    #pragma unroll
    for (int jj = 0; jj < 8; ++jj)
      gld16(src + (jj * 256 + tid) * 8, &Bl[buf][(jj * 256 + w * 64) * 8]);
    if (tid < 64) ncs[buf][tid] = nrm[colslice + t * 64 + tid];
  };

  stage(0, 0);
  for (int t = 0; t < 16; ++t) {
    const int cur = t & 1;
    __syncthreads();                       // drains vmcnt: Bl[cur] ready
    if (t + 1 < 16) stage(cur ^ 1, t + 1); // prefetch overlaps compute
    const int cbase = colslice + t * 64;
    f32x4 acc[4][2];
    #pragma unroll
    for (int rf = 0; rf < 4; ++rf) {
      f32x4 z = {0.f, 0.f, 0.f, 0.f};
      acc[rf][0] = z; acc[rf][1] = z;
    }
    #pragma unroll
    for (int kf = 0; kf < 8; ++kf) {
      const int gs = ((kf << 2) | l4) ^ (l15 & 7);
      const s8v b0 = *reinterpret_cast<const s8v*>(&Bl[cur][(wcol + l15) * NK + gs * 8]);
      const s8v b1 = *reinterpret_cast<const s8v*>(&Bl[cur][(wcol + 16 + l15) * NK + gs * 8]);
      #pragma unroll
      for (int rf = 0; rf < 4; ++rf) {
        acc[rf][0] = __builtin_amdgcn_mfma_f32_16x16x32_bf16(A[rf][kf], b0, acc[rf][0], 0, 0, 0);
        acc[rf][1] = __builtin_amdgcn_mfma_f32_16x16x32_bf16(A[rf][kf], b1, acc[rf][1], 0, 0, 0);
      }
    }
    // epilogue: d, denom, tau-filtered passer append
    #pragma unroll
    for (int rf = 0; rf < 4; ++rf)
      #pragma unroll
      for (int cf = 0; cf < 2; ++cf) {
        const int colg = cbase + wcol + cf * 16 + l15;
        const float nc = ncs[cur][wcol + cf * 16 + l15];
        #pragma unroll
        for (int q = 0; q < 4; ++q) {
          const int rowg = rowbase + rf * 16 + l4 * 4 + q;
          const float dd = distf(acc[rf][cf][q], nr[rf][q] + nc);
          const bool nd = (rowg != colg);
          dn[rf][q] += nd ? __expf(-dd) : 0.0f;
          const unsigned d16 = (unsigned)__half_as_ushort(__float2half(dd));
          if (nd && d16 <= tk[rf][q]) {
            const unsigned slot = atomicAdd(&cnt[rowg], 1u);
            if (slot < CAP)
              pass[rowg * CAP + slot] = (d16 << 16) | (unsigned)colg;
          }
        }
      }
  }
  // per-row denom partial: reduce across the 16 lanes holding the same row
  #pragma unroll
  for (int rf = 0; rf < 4; ++rf)
    #pragma unroll
    for (int q = 0; q < 4; ++q) {
      float vs = dn[rf][q];
      vs += __shfl_xor(vs, 1); vs += __shfl_xor(vs, 2);
      vs += __shfl_xor(vs, 4); vs += __shfl_xor(vs, 8);
      if (l15 == 0) atomicAdd(&denom[rowbase + rf * 16 + l4 * 4 + q], vs);
    }
}

// ----------------------------------------------------------------- k_fin ----
__global__ __launch_bounds__(256) void k_fin(const unsigned* __restrict__ pass,
                                             const unsigned* __restrict__ cnt,
                                             const float* __restrict__ denom,
                                             const int* __restrict__ y,
                                             float* __restrict__ out) {
  const int w = threadIdx.x >> 6, l = threadIdx.x & 63;
  const int r = blockIdx.x * 4 + w;
  const unsigned c = umin32(cnt[r], (unsigned)CAP);
  unsigned kk[8];
  #pragma unroll
  for (int j = 0; j < 8; ++j) {
    const unsigned slot = (unsigned)l + 64u * j;
    kk[j] = (slot < c) ? pass[r * CAP + slot] : 0xFFFFFFFFu;
  }
  unsigned myKey = 0xFFFFFFFFu;
  for (int pp = 0; pp < 16; ++pp) {
    unsigned lm = kk[0];
    #pragma unroll
    for (int j = 1; j < 8; ++j) lm = umin32(lm, kk[j]);
    unsigned m = lm;
    m = umin32(m, __shfl_xor(m, 1));  m = umin32(m, __shfl_xor(m, 2));
    m = umin32(m, __shfl_xor(m, 4));  m = umin32(m, __shfl_xor(m, 8));
    m = umin32(m, __shfl_xor(m, 16)); m = umin32(m, __shfl_xor(m, 32));
    const unsigned long long bal = __ballot(lm == m);
    const int owner = (int)__ffsll(bal) - 1;
    if (l == owner) {
      bool f = false;
      #pragma unroll
      for (int j = 0; j < 8; ++j)
        if (!f && kk[j] == m) { kk[j] = 0xFFFFFFFFu; f = true; }
    }
    if (l == pp) myKey = m;  // lanes 0..15 collect the 16 nearest keys
  }
  const float logden = __logf(denom[r]);
  float contrib = 0.0f, cmf = 0.0f;
  if (l < 16 && myKey != 0xFFFFFFFFu) {
    const int col = (int)(myKey & 0xFFFFu);
    const float dd = __half2float(__ushort_as_half((unsigned short)(myKey >> 16)));
    if (y[col] == y[r]) { contrib = -dd - logden; cmf = 1.0f; }
  }
  contrib += __shfl_xor(contrib, 1);  contrib += __shfl_xor(contrib, 2);
  contrib += __shfl_xor(contrib, 4);  contrib += __shfl_xor(contrib, 8);
  contrib += __shfl_xor(contrib, 16); contrib += __shfl_xor(contrib, 32);
  cmf += __shfl_xor(cmf, 1);  cmf += __shfl_xor(cmf, 2);
  cmf += __shfl_xor(cmf, 4);  cmf += __shfl_xor(cmf, 8);
  cmf += __shfl_xor(cmf, 16); cmf += __shfl_xor(cmf, 32);
  if (l == 0 && cmf > 0.0f)
    atomicAdd(out, (contrib / cmf) * (-1.0f / 8192.0f));
}

// ---------------------------------------------------------------------------
extern "C" void kernel_launch(void* const* d_in, const int* in_sizes, int n_in,
                              void* d_out, int out_size, void* d_ws, size_t ws_size,
                              hipStream_t stream) {
  const float* x = (const float*)d_in[0];
  const int* y = (const int*)d_in[1];
  float* out = (float*)d_out;
  char* ws = (char*)d_ws;

  unsigned*       cnt   = (unsigned*)(ws + OFF_CNT);
  float*          denom = (float*)(ws + OFF_DEN);
  float*          nrm   = (float*)(ws + OFF_NRM);
  unsigned*       tauk  = (unsigned*)(ws + OFF_TAU);
  unsigned short* xb    = (unsigned short*)(ws + OFF_XB);
  unsigned short* samp  = (unsigned short*)(ws + OFF_SAMP);
  unsigned*       pass  = (unsigned*)(ws + OFF_SAMP);  // reuse after k_tau

  hipMemsetAsync(ws + OFF_CNT, 0, 65536, stream);      // cnt + denom
  hipMemsetAsync(d_out, 0, sizeof(float), stream);

  k_prep<<<2048, 256, 0, stream>>>(x, xb, nrm);
  k_samp<<<256,  256, 0, stream>>>(xb, nrm, samp);
  k_tau <<<2048, 256, 0, stream>>>(samp, tauk);
  k_main<<<512,  256, 0, stream>>>(xb, nrm, tauk, denom, cnt, pass);
  k_fin <<<2048, 256, 0, stream>>>(pass, cnt, denom, y, out);
}

// Round 2
// 185.736 us; speedup vs baseline: 2.6512x; 2.6512x over previous
//
#include <hip/hip_runtime.h>
#include <hip/hip_fp16.h>

// ---------------------------------------------------------------------------
// ClassificationKNNLoss on MI355X — fused, distance matrix never materialized.
//   k_prep : norms + bf16 convert with granule-XOR swizzle
//   k_samp : MFMA GEMM over 1024 sampled cols/row -> f16 distances (subset)
//   k_tau  : per-row 16th-smallest sample = conservative threshold tau
//   k_main : full GEMM; d, exp(-d)->denom; d16<=tau -> passer append via
//            LDS slot counter (NO global atomics in hot loop — R1 lesson:
//            ~860K serialized device-scope atomic RMWs cost ~380 us)
//   k_fin  : per-row top-16 of passers, label match, loss reduction
// ---------------------------------------------------------------------------

typedef __attribute__((ext_vector_type(8))) short s8v;    // 8 x bf16 (4 VGPR)
typedef __attribute__((ext_vector_type(4))) float f32x4;  // MFMA acc

#define NROW 8192
#define NK   256
#define SAMPN 1024
#define SLOT 64   // passer slots per (row, col-slice); E[passers]=16, P(>64)~1e-5

// ws byte offsets
#define OFF_DEN  0                          // f32[8192]
#define OFF_NRM  32768                      // f32[8192]
#define OFF_TAU  65536                      // u32[8192]
#define OFF_GCNT 98304                      // u32[8192*8] counts per (row,cs)
#define OFF_XB   360448                     // u16[8192*256] swizzled bf16 (4.19MB)
#define OFF_SAMP (OFF_XB + NROW * NK * 2)   // u16[8192*1024]; reused as pass u32[8192*8*64]

__device__ __forceinline__ unsigned short f2bf(float f) {
  unsigned u = __float_as_uint(f);
  return (unsigned short)((u + 0x7FFFu + ((u >> 16) & 1u)) >> 16);  // RNE
}

// identical expression in k_samp and k_main -> bitwise-equal d for sampled cols
__device__ __forceinline__ float distf(float acc, float s) {
  return sqrtf(fmaxf(fmaf(acc, -2.0f, s), 0.0f));
}

__device__ __forceinline__ void gld16(const void* g, void* l) {
  __builtin_amdgcn_global_load_lds(
      (const __attribute__((address_space(1))) unsigned int*)g,
      (__attribute__((address_space(3))) unsigned int*)l, 16, 0, 0);
}

__device__ __forceinline__ unsigned umin32(unsigned a, unsigned b) { return a < b ? a : b; }

// ---------------------------------------------------------------- k_prep ----
// xb[(r,k)] stored at u16 index r*256 + ((k>>3) ^ (r&7))*8 + (k&7)
__global__ __launch_bounds__(256) void k_prep(const float* __restrict__ x,
                                              unsigned short* __restrict__ xb,
                                              float* __restrict__ nrm) {
  const int w = threadIdx.x >> 6, l = threadIdx.x & 63;
  const int r = blockIdx.x * 4 + w;
  const float4 xv = *reinterpret_cast<const float4*>(x + r * NK + l * 4);
  float ns = xv.x * xv.x + xv.y * xv.y + xv.z * xv.z + xv.w * xv.w;
  ns += __shfl_xor(ns, 1);  ns += __shfl_xor(ns, 2);  ns += __shfl_xor(ns, 4);
  ns += __shfl_xor(ns, 8);  ns += __shfl_xor(ns, 16); ns += __shfl_xor(ns, 32);
  if (l == 0) nrm[r] = ns;
  ushort4 bv;
  bv.x = f2bf(xv.x); bv.y = f2bf(xv.y); bv.z = f2bf(xv.z); bv.w = f2bf(xv.w);
  const int gs = (l >> 1) ^ (r & 7);
  *reinterpret_cast<ushort4*>(xb + r * NK + gs * 8 + (l & 1) * 4) = bv;
}

// ---------------------------------------------------------------- k_samp ----
// Sampled col s (0..1023) -> global row j(s) = 8s + (s&7)  ((j&7)==(s&7) keeps
// the granule swizzle consistent with tile position).  512 thr = 8 waves.
__global__ __launch_bounds__(512) void k_samp(const unsigned short* __restrict__ xb,
                                              const float* __restrict__ nrm,
                                              unsigned short* __restrict__ samp) {
  __shared__ __align__(16) unsigned short Bl[2][64 * NK];  // 2 x 32KB
  __shared__ float ncs[2][64];
  const int tid = threadIdx.x;
  const int w = tid >> 6, l = tid & 63, l15 = l & 15, l4 = l >> 4;
  const int rb = blockIdx.x >> 2, ss = blockIdx.x & 3;
  const int rowbase = rb * 128 + (w >> 1) * 32;
  const int wcol = (w & 1) * 32;
  const int sbase = ss * 256;

  s8v A[2][8];
  #pragma unroll
  for (int rf = 0; rf < 2; ++rf) {
    const int rr = rowbase + rf * 16 + l15;
    #pragma unroll
    for (int kf = 0; kf < 8; ++kf) {
      const int g = ((kf << 2) | l4) ^ (rr & 7);
      A[rf][kf] = *reinterpret_cast<const s8v*>(xb + rr * NK + g * 8);
    }
  }
  float nr[2][4];
  #pragma unroll
  for (int rf = 0; rf < 2; ++rf)
    #pragma unroll
    for (int q = 0; q < 4; ++q) nr[rf][q] = nrm[rowbase + rf * 16 + l4 * 4 + q];

  auto stage = [&](int buf, int t) {
    #pragma unroll
    for (int jj = 0; jj < 4; ++jj) {
      const int unit = jj * 512 + tid;
      const int sc = unit >> 5, gsl = unit & 31;
      const int si = sbase + t * 64 + sc;
      const int jrow = si * 8 + (si & 7);
      gld16(xb + jrow * NK + gsl * 8, &Bl[buf][(jj * 512 + w * 64) * 8]);
    }
    if (tid < 64) {
      const int si = sbase + t * 64 + tid;
      ncs[buf][tid] = nrm[si * 8 + (si & 7)];
    }
  };

  stage(0, 0);
  for (int t = 0; t < 4; ++t) {
    const int cur = t & 1;
    __syncthreads();
    if (t + 1 < 4) stage(cur ^ 1, t + 1);
    f32x4 acc[2][2];
    #pragma unroll
    for (int rf = 0; rf < 2; ++rf) {
      f32x4 z = {0.f, 0.f, 0.f, 0.f};
      acc[rf][0] = z; acc[rf][1] = z;
    }
    #pragma unroll
    for (int kf = 0; kf < 8; ++kf) {
      const int gs = ((kf << 2) | l4) ^ (l15 & 7);
      const s8v b0 = *reinterpret_cast<const s8v*>(&Bl[cur][(wcol + l15) * NK + gs * 8]);
      const s8v b1 = *reinterpret_cast<const s8v*>(&Bl[cur][(wcol + 16 + l15) * NK + gs * 8]);
      #pragma unroll
      for (int rf = 0; rf < 2; ++rf) {
        acc[rf][0] = __builtin_amdgcn_mfma_f32_16x16x32_bf16(A[rf][kf], b0, acc[rf][0], 0, 0, 0);
        acc[rf][1] = __builtin_amdgcn_mfma_f32_16x16x32_bf16(A[rf][kf], b1, acc[rf][1], 0, 0, 0);
      }
    }
    #pragma unroll
    for (int rf = 0; rf < 2; ++rf)
      #pragma unroll
      for (int cf = 0; cf < 2; ++cf) {
        const int scol = sbase + t * 64 + wcol + cf * 16 + l15;
        const int jcol = scol * 8 + (scol & 7);
        const float nc = ncs[cur][wcol + cf * 16 + l15];
        #pragma unroll
        for (int q = 0; q < 4; ++q) {
          const int rowg = rowbase + rf * 16 + l4 * 4 + q;
          const float dd = distf(acc[rf][cf][q], nr[rf][q] + nc);
          unsigned short d16 = __half_as_ushort(__float2half(dd));
          if (jcol == rowg) d16 = 0xFFFFu;  // exclude self
          samp[rowg * SAMPN + scol] = d16;
        }
      }
  }
}

// ----------------------------------------------------------------- k_tau ----
__global__ __launch_bounds__(256) void k_tau(const unsigned short* __restrict__ samp,
                                             unsigned* __restrict__ tauk) {
  const int w = threadIdx.x >> 6, l = threadIdx.x & 63;
  const int r = blockIdx.x * 4 + w;
  const uint4* sp = reinterpret_cast<const uint4*>(samp + r * SAMPN + l * 16);
  const uint4 pa = sp[0], pb = sp[1];
  unsigned v[16];
  v[0] = pa.x & 0xFFFFu;  v[1] = pa.x >> 16;  v[2] = pa.y & 0xFFFFu;  v[3] = pa.y >> 16;
  v[4] = pa.z & 0xFFFFu;  v[5] = pa.z >> 16;  v[6] = pa.w & 0xFFFFu;  v[7] = pa.w >> 16;
  v[8] = pb.x & 0xFFFFu;  v[9] = pb.x >> 16;  v[10] = pb.y & 0xFFFFu; v[11] = pb.y >> 16;
  v[12] = pb.z & 0xFFFFu; v[13] = pb.z >> 16; v[14] = pb.w & 0xFFFFu; v[15] = pb.w >> 16;
  unsigned m = 0;
  for (int pp = 0; pp < 16; ++pp) {
    unsigned lm = v[0];
    #pragma unroll
    for (int j = 1; j < 16; ++j) lm = umin32(lm, v[j]);
    m = lm;
    m = umin32(m, __shfl_xor(m, 1));  m = umin32(m, __shfl_xor(m, 2));
    m = umin32(m, __shfl_xor(m, 4));  m = umin32(m, __shfl_xor(m, 8));
    m = umin32(m, __shfl_xor(m, 16)); m = umin32(m, __shfl_xor(m, 32));
    const unsigned long long bal = __ballot(lm == m);
    const int owner = (int)__ffsll(bal) - 1;
    if (l == owner) {
      bool f = false;
      #pragma unroll
      for (int j = 0; j < 16; ++j)
        if (!f && v[j] == m) { v[j] = 0xFFFFFFFFu; f = true; }
    }
  }
  if (l == 0) tauk[r] = m;
}

// ---------------------------------------------------------------- k_main ----
__global__ __launch_bounds__(512) void k_main(const unsigned short* __restrict__ xb,
                                              const float* __restrict__ nrm,
                                              const unsigned* __restrict__ tauk,
                                              float* __restrict__ denom,
                                              unsigned* __restrict__ gcnt,
                                              unsigned* __restrict__ pass) {
  __shared__ __align__(16) unsigned short Bl[2][64 * NK];  // 2 x 32KB dbuf
  __shared__ float ncs[2][64];
  __shared__ unsigned qcnt[128];                           // per-row slot counters
  const int tid = threadIdx.x;
  const int w = tid >> 6, l = tid & 63, l15 = l & 15, l4 = l >> 4;
  const int rb = blockIdx.x >> 3, cs = blockIdx.x & 7;
  const int rowbase = rb * 128 + (w >> 1) * 32;
  const int wcol = (w & 1) * 32;
  const int colslice = cs * 1024;

  if (tid < 128) qcnt[tid] = 0;

  s8v A[2][8];  // 32 rows x K=256 in registers, reused across all 16 col-tiles
  #pragma unroll
  for (int rf = 0; rf < 2; ++rf) {
    const int rr = rowbase + rf * 16 + l15;
    #pragma unroll
    for (int kf = 0; kf < 8; ++kf) {
      const int g = ((kf << 2) | l4) ^ (rr & 7);
      A[rf][kf] = *reinterpret_cast<const s8v*>(xb + rr * NK + g * 8);
    }
  }
  float nr[2][4]; unsigned tk[2][4];
  #pragma unroll
  for (int rf = 0; rf < 2; ++rf)
    #pragma unroll
    for (int q = 0; q < 4; ++q) {
      const int rowg = rowbase + rf * 16 + l4 * 4 + q;
      nr[rf][q] = nrm[rowg];
      tk[rf][q] = tauk[rowg];
    }
  float dn[2][4] = {};

  auto stage = [&](int buf, int t) {
    const unsigned short* src = xb + (colslice + t * 64) * NK;  // linear 32KB
    #pragma unroll
    for (int jj = 0; jj < 4; ++jj)
      gld16(src + (jj * 512 + tid) * 8, &Bl[buf][(jj * 512 + w * 64) * 8]);
    if (tid < 64) ncs[buf][tid] = nrm[colslice + t * 64 + tid];
  };

  stage(0, 0);
  for (int t = 0; t < 16; ++t) {
    const int cur = t & 1;
    __syncthreads();                        // Bl[cur] ready (also covers qcnt init)
    if (t + 1 < 16) stage(cur ^ 1, t + 1);  // prefetch overlaps compute
    const int cbase = colslice + t * 64;
    f32x4 acc[2][2];
    #pragma unroll
    for (int rf = 0; rf < 2; ++rf) {
      f32x4 z = {0.f, 0.f, 0.f, 0.f};
      acc[rf][0] = z; acc[rf][1] = z;
    }
    #pragma unroll
    for (int kf = 0; kf < 8; ++kf) {
      const int gs = ((kf << 2) | l4) ^ (l15 & 7);
      const s8v b0 = *reinterpret_cast<const s8v*>(&Bl[cur][(wcol + l15) * NK + gs * 8]);
      const s8v b1 = *reinterpret_cast<const s8v*>(&Bl[cur][(wcol + 16 + l15) * NK + gs * 8]);
      #pragma unroll
      for (int rf = 0; rf < 2; ++rf) {
        acc[rf][0] = __builtin_amdgcn_mfma_f32_16x16x32_bf16(A[rf][kf], b0, acc[rf][0], 0, 0, 0);
        acc[rf][1] = __builtin_amdgcn_mfma_f32_16x16x32_bf16(A[rf][kf], b1, acc[rf][1], 0, 0, 0);
      }
    }
    // epilogue: d, denom; passer append via LDS counter + fire-and-forget store
    #pragma unroll
    for (int rf = 0; rf < 2; ++rf)
      #pragma unroll
      for (int cf = 0; cf < 2; ++cf) {
        const int colg = cbase + wcol + cf * 16 + l15;
        const float nc = ncs[cur][wcol + cf * 16 + l15];
        #pragma unroll
        for (int q = 0; q < 4; ++q) {
          const int rowg = rowbase + rf * 16 + l4 * 4 + q;
          const float dd = distf(acc[rf][cf][q], nr[rf][q] + nc);
          const bool nd = (rowg != colg);
          dn[rf][q] += nd ? __expf(-dd) : 0.0f;
          const unsigned d16 = (unsigned)__half_as_ushort(__float2half(dd));
          if (nd && d16 <= tk[rf][q]) {
            const unsigned slot = atomicAdd(&qcnt[rowg - rb * 128], 1u);  // LDS atomic
            if (slot < SLOT)
              pass[(rowg * 8 + cs) * SLOT + slot] = (d16 << 16) | (unsigned)colg;
          }
        }
      }
  }
  // per-row denom partial: reduce across the 16 lanes holding the same row
  #pragma unroll
  for (int rf = 0; rf < 2; ++rf)
    #pragma unroll
    for (int q = 0; q < 4; ++q) {
      float vs = dn[rf][q];
      vs += __shfl_xor(vs, 1); vs += __shfl_xor(vs, 2);
      vs += __shfl_xor(vs, 4); vs += __shfl_xor(vs, 8);
      if (l15 == 0) atomicAdd(&denom[rowbase + rf * 16 + l4 * 4 + q], vs);
    }
  __syncthreads();
  if (tid < 128) gcnt[(rb * 128 + tid) * 8 + cs] = umin32(qcnt[tid], (unsigned)SLOT);
}

// ----------------------------------------------------------------- k_fin ----
__global__ __launch_bounds__(256) void k_fin(const unsigned* __restrict__ pass,
                                             const unsigned* __restrict__ gcnt,
                                             const float* __restrict__ denom,
                                             const int* __restrict__ y,
                                             float* __restrict__ out) {
  const int w = threadIdx.x >> 6, l = threadIdx.x & 63;
  const int r = blockIdx.x * 4 + w;
  unsigned kk[8];
  #pragma unroll
  for (int cs = 0; cs < 8; ++cs) {
    const unsigned c = gcnt[r * 8 + cs];  // already clamped <= SLOT
    kk[cs] = ((unsigned)l < c) ? pass[(r * 8 + cs) * SLOT + l] : 0xFFFFFFFFu;
  }
  unsigned myKey = 0xFFFFFFFFu;
  for (int pp = 0; pp < 16; ++pp) {
    unsigned lm = kk[0];
    #pragma unroll
    for (int j = 1; j < 8; ++j) lm = umin32(lm, kk[j]);
    unsigned m = lm;
    m = umin32(m, __shfl_xor(m, 1));  m = umin32(m, __shfl_xor(m, 2));
    m = umin32(m, __shfl_xor(m, 4));  m = umin32(m, __shfl_xor(m, 8));
    m = umin32(m, __shfl_xor(m, 16)); m = umin32(m, __shfl_xor(m, 32));
    const unsigned long long bal = __ballot(lm == m);
    const int owner = (int)__ffsll(bal) - 1;
    if (l == owner) {
      bool f = false;
      #pragma unroll
      for (int j = 0; j < 8; ++j)
        if (!f && kk[j] == m) { kk[j] = 0xFFFFFFFFu; f = true; }
    }
    if (l == pp) myKey = m;  // lanes 0..15 collect the 16 nearest keys
  }
  const float logden = __logf(denom[r]);
  float contrib = 0.0f, cmf = 0.0f;
  if (l < 16 && myKey != 0xFFFFFFFFu) {
    const int col = (int)(myKey & 0xFFFFu);
    const float dd = __half2float(__ushort_as_half((unsigned short)(myKey >> 16)));
    if (y[col] == y[r]) { contrib = -dd - logden; cmf = 1.0f; }
  }
  contrib += __shfl_xor(contrib, 1);  contrib += __shfl_xor(contrib, 2);
  contrib += __shfl_xor(contrib, 4);  contrib += __shfl_xor(contrib, 8);
  contrib += __shfl_xor(contrib, 16); contrib += __shfl_xor(contrib, 32);
  cmf += __shfl_xor(cmf, 1);  cmf += __shfl_xor(cmf, 2);
  cmf += __shfl_xor(cmf, 4);  cmf += __shfl_xor(cmf, 8);
  cmf += __shfl_xor(cmf, 16); cmf += __shfl_xor(cmf, 32);
  if (l == 0 && cmf > 0.0f)
    atomicAdd(out, (contrib / cmf) * (-1.0f / 8192.0f));
}

// ---------------------------------------------------------------------------
extern "C" void kernel_launch(void* const* d_in, const int* in_sizes, int n_in,
                              void* d_out, int out_size, void* d_ws, size_t ws_size,
                              hipStream_t stream) {
  const float* x = (const float*)d_in[0];
  const int* y = (const int*)d_in[1];
  float* out = (float*)d_out;
  char* ws = (char*)d_ws;

  float*          denom = (float*)(ws + OFF_DEN);
  float*          nrm   = (float*)(ws + OFF_NRM);
  unsigned*       tauk  = (unsigned*)(ws + OFF_TAU);
  unsigned*       gcnt  = (unsigned*)(ws + OFF_GCNT);
  unsigned short* xb    = (unsigned short*)(ws + OFF_XB);
  unsigned short* samp  = (unsigned short*)(ws + OFF_SAMP);
  unsigned*       pass  = (unsigned*)(ws + OFF_SAMP);  // reuse after k_tau

  hipMemsetAsync(ws + OFF_DEN, 0, 32768, stream);  // denom only
  hipMemsetAsync(d_out, 0, sizeof(float), stream);

  k_prep<<<2048, 256, 0, stream>>>(x, xb, nrm);
  k_samp<<<256,  512, 0, stream>>>(xb, nrm, samp);
  k_tau <<<2048, 256, 0, stream>>>(samp, tauk);
  k_main<<<512,  512, 0, stream>>>(xb, nrm, tauk, denom, gcnt, pass);
  k_fin <<<2048, 256, 0, stream>>>(pass, gcnt, denom, y, out);
}

// Round 3
// 133.588 us; speedup vs baseline: 3.6861x; 1.3904x over previous
//
#include <hip/hip_runtime.h>
#include <hip/hip_fp16.h>

// ---------------------------------------------------------------------------
// ClassificationKNNLoss on MI355X — fused, distance matrix never materialized.
//   k_prep : norms + bf16 convert with granule-XOR swizzle
//   k_samp : MFMA GEMM over 512 sampled cols/row -> f16 distances
//   k_tau  : per-row 6th-smallest sample = conservative threshold tau
//   k_main : full GEMM; d, exp(-d)->denom partials; sq<tau^2 -> passer store
//            with BALLOT-ranked slots (no atomics at all in hot loop —
//            R2 lesson: per-passer ds_add_rtn serialization was the stall)
//   k_fin  : per-row top-16 of passers, label match, loss reduction
// ---------------------------------------------------------------------------

typedef __attribute__((ext_vector_type(8))) short s8v;    // 8 x bf16 (4 VGPR)
typedef __attribute__((ext_vector_type(4))) float f32x4;  // MFMA acc

#define NROW 8192
#define NK   256
#define SAMPN 512
#define TAUR  6    // tau = 6th smallest of 512 samples -> E[passers/row] = 96
#define PSLOT 2    // slots per (row, 64-col tile, cf16); P(overflow)~1e-3/group

template <bool B> struct BoolC { static constexpr bool value = B; };

// ws byte offsets
#define OFF_DNP  0                          // f32[8192*8] denom partials (256KB)
#define OFF_NRM  262144                     // f32[8192]
#define OFF_TAU  294912                     // u32[8192]
#define OFF_XB   327680                     // u16[8192*256] swizzled bf16 (4.19MB)
#define OFF_SAMP 4521984                    // u16[8192*512] (8.4MB); reused as
#define OFF_PASS 4521984                    // u32[8192*512] passers (16.8MB)
#define PASS_BYTES (NROW * 512 * 4)

__device__ __forceinline__ unsigned short f2bf(float f) {
  unsigned u = __float_as_uint(f);
  return (unsigned short)((u + 0x7FFFu + ((u >> 16) & 1u)) >> 16);  // RNE
}

__device__ __forceinline__ void gld16(const void* g, void* l) {
  __builtin_amdgcn_global_load_lds(
      (const __attribute__((address_space(1))) unsigned int*)g,
      (__attribute__((address_space(3))) unsigned int*)l, 16, 0, 0);
}

__device__ __forceinline__ unsigned umin32(unsigned a, unsigned b) { return a < b ? a : b; }

// ---------------------------------------------------------------- k_prep ----
// xb[(r,k)] stored at u16 index r*256 + ((k>>3) ^ (r&7))*8 + (k&7)
__global__ __launch_bounds__(256) void k_prep(const float* __restrict__ x,
                                              unsigned short* __restrict__ xb,
                                              float* __restrict__ nrm) {
  const int w = threadIdx.x >> 6, l = threadIdx.x & 63;
  const int r = blockIdx.x * 4 + w;
  const float4 xv = *reinterpret_cast<const float4*>(x + r * NK + l * 4);
  float ns = xv.x * xv.x + xv.y * xv.y + xv.z * xv.z + xv.w * xv.w;
  ns += __shfl_xor(ns, 1);  ns += __shfl_xor(ns, 2);  ns += __shfl_xor(ns, 4);
  ns += __shfl_xor(ns, 8);  ns += __shfl_xor(ns, 16); ns += __shfl_xor(ns, 32);
  if (l == 0) nrm[r] = ns;
  ushort4 bv;
  bv.x = f2bf(xv.x); bv.y = f2bf(xv.y); bv.z = f2bf(xv.z); bv.w = f2bf(xv.w);
  const int gs = (l >> 1) ^ (r & 7);
  *reinterpret_cast<ushort4*>(xb + r * NK + gs * 8 + (l & 1) * 4) = bv;
}

// ---------------------------------------------------------------- k_samp ----
// Sample s (0..511) -> global row j(s) = 16s + (s&7) ((j&7)==(s&7) keeps the
// granule swizzle consistent with tile position). One 64-sample tile / block.
__global__ __launch_bounds__(512) void k_samp(const unsigned short* __restrict__ xb,
                                              const float* __restrict__ nrm,
                                              unsigned short* __restrict__ samp) {
  __shared__ __align__(16) unsigned short Bl[64 * NK];  // 32KB
  __shared__ float ncs[64];
  const int tid = threadIdx.x;
  const int w = tid >> 6, l = tid & 63, l15 = l & 15, l4 = l >> 4;
  const int rb = blockIdx.x >> 3, ss = blockIdx.x & 7;
  const int rowbase = rb * 128 + (w >> 1) * 32;
  const int wcol = (w & 1) * 32;

  #pragma unroll
  for (int jj = 0; jj < 4; ++jj) {
    const int unit = jj * 512 + tid;
    const int sc = unit >> 5, gsl = unit & 31;
    const int s = ss * 64 + sc;
    const int jrow = s * 16 + (s & 7);
    gld16(xb + jrow * NK + gsl * 8, &Bl[unit * 8]);
  }
  if (tid < 64) {
    const int s = ss * 64 + tid;
    ncs[tid] = nrm[s * 16 + (s & 7)];
  }

  s8v A[2][8];
  #pragma unroll
  for (int rf = 0; rf < 2; ++rf) {
    const int rr = rowbase + rf * 16 + l15;
    #pragma unroll
    for (int kf = 0; kf < 8; ++kf) {
      const int g = ((kf << 2) | l4) ^ (rr & 7);
      A[rf][kf] = *reinterpret_cast<const s8v*>(xb + rr * NK + g * 8);
    }
  }
  float nr[2][4];
  #pragma unroll
  for (int rf = 0; rf < 2; ++rf)
    #pragma unroll
    for (int q = 0; q < 4; ++q) nr[rf][q] = nrm[rowbase + rf * 16 + l4 * 4 + q];

  __syncthreads();
  f32x4 acc[2][2];
  #pragma unroll
  for (int rf = 0; rf < 2; ++rf) {
    f32x4 z = {0.f, 0.f, 0.f, 0.f};
    acc[rf][0] = z; acc[rf][1] = z;
  }
  #pragma unroll
  for (int kf = 0; kf < 8; ++kf) {
    const int gs = ((kf << 2) | l4) ^ (l15 & 7);
    const s8v b0 = *reinterpret_cast<const s8v*>(&Bl[(wcol + l15) * NK + gs * 8]);
    const s8v b1 = *reinterpret_cast<const s8v*>(&Bl[(wcol + 16 + l15) * NK + gs * 8]);
    #pragma unroll
    for (int rf = 0; rf < 2; ++rf) {
      acc[rf][0] = __builtin_amdgcn_mfma_f32_16x16x32_bf16(A[rf][kf], b0, acc[rf][0], 0, 0, 0);
      acc[rf][1] = __builtin_amdgcn_mfma_f32_16x16x32_bf16(A[rf][kf], b1, acc[rf][1], 0, 0, 0);
    }
  }
  #pragma unroll
  for (int rf = 0; rf < 2; ++rf)
    #pragma unroll
    for (int cf = 0; cf < 2; ++cf) {
      const int scol = ss * 64 + wcol + cf * 16 + l15;
      const int jcol = scol * 16 + (scol & 7);
      const float nc = ncs[wcol + cf * 16 + l15];
      #pragma unroll
      for (int q = 0; q < 4; ++q) {
        const int rowg = rowbase + rf * 16 + l4 * 4 + q;
        const float sq = fmaxf(fmaf(acc[rf][cf][q], -2.0f, nr[rf][q] + nc), 0.0f);
        const float dd = __builtin_amdgcn_sqrtf(sq);
        unsigned short d16 = __half_as_ushort(__float2half(dd));
        if (jcol == rowg) d16 = 0xFFFFu;  // exclude self
        samp[rowg * SAMPN + scol] = d16;
      }
    }
}

// ----------------------------------------------------------------- k_tau ----
__global__ __launch_bounds__(256) void k_tau(const unsigned short* __restrict__ samp,
                                             unsigned* __restrict__ tauk) {
  const int w = threadIdx.x >> 6, l = threadIdx.x & 63;
  const int r = blockIdx.x * 4 + w;
  const uint4 pa = *reinterpret_cast<const uint4*>(samp + r * SAMPN + l * 8);
  unsigned v[8];
  v[0] = pa.x & 0xFFFFu; v[1] = pa.x >> 16; v[2] = pa.y & 0xFFFFu; v[3] = pa.y >> 16;
  v[4] = pa.z & 0xFFFFu; v[5] = pa.z >> 16; v[6] = pa.w & 0xFFFFu; v[7] = pa.w >> 16;
  unsigned m = 0;
  for (int pp = 0; pp < TAUR; ++pp) {
    unsigned lm = v[0];
    #pragma unroll
    for (int j = 1; j < 8; ++j) lm = umin32(lm, v[j]);
    m = lm;
    m = umin32(m, __shfl_xor(m, 1));  m = umin32(m, __shfl_xor(m, 2));
    m = umin32(m, __shfl_xor(m, 4));  m = umin32(m, __shfl_xor(m, 8));
    m = umin32(m, __shfl_xor(m, 16)); m = umin32(m, __shfl_xor(m, 32));
    const unsigned long long bal = __ballot(lm == m);
    const int owner = (int)__ffsll(bal) - 1;
    if (l == owner) {
      bool f = false;
      #pragma unroll
      for (int j = 0; j < 8; ++j)
        if (!f && v[j] == m) { v[j] = 0xFFFFFFFFu; f = true; }
    }
  }
  if (l == 0) tauk[r] = m;
}

// ---------------------------------------------------------------- k_main ----
__global__ __launch_bounds__(512) void k_main(const unsigned short* __restrict__ xb,
                                              const float* __restrict__ nrm,
                                              const unsigned* __restrict__ tauk,
                                              float* __restrict__ dnp,
                                              unsigned* __restrict__ pass) {
  __shared__ __align__(16) unsigned short Bl[2][64 * NK];  // 2 x 32KB dbuf
  __shared__ float ncs[2][64];
  __shared__ float dpart[128];
  const int tid = threadIdx.x;
  const int w = tid >> 6, l = tid & 63, l15 = l & 15, l4 = l >> 4;
  const int rb = blockIdx.x >> 3, cs = blockIdx.x & 7;
  const int rowbase = rb * 128 + (w >> 1) * 32;
  const int wcol = (w & 1) * 32;
  const int colslice = cs * 1024;
  const unsigned long long ltm = (1ull << l) - 1ull;
  const unsigned long long sub = 0xFFFFull << (l4 * 16);

  if (tid < 128) dpart[tid] = 0.0f;

  s8v A[2][8];  // 32 rows x K=256 in registers, reused across all 16 col-tiles
  #pragma unroll
  for (int rf = 0; rf < 2; ++rf) {
    const int rr = rowbase + rf * 16 + l15;
    #pragma unroll
    for (int kf = 0; kf < 8; ++kf) {
      const int g = ((kf << 2) | l4) ^ (rr & 7);
      A[rf][kf] = *reinterpret_cast<const s8v*>(xb + rr * NK + g * 8);
    }
  }
  float nr[2][4], tk2[2][4], dn[2][4];
  #pragma unroll
  for (int rf = 0; rf < 2; ++rf)
    #pragma unroll
    for (int q = 0; q < 4; ++q) {
      const int rowg = rowbase + rf * 16 + l4 * 4 + q;
      nr[rf][q] = nrm[rowg];
      // widened tau: f16(tau)+1ulp as f32, squared -> filter in sq domain
      const float tw = __half2float(__ushort_as_half((unsigned short)(tauk[rowg] + 1u)));
      tk2[rf][q] = tw * tw;
      dn[rf][q] = 0.0f;
    }

  auto stage = [&](int buf, int t) {
    const unsigned short* src = xb + (colslice + t * 64) * NK;  // linear 32KB
    #pragma unroll
    for (int jj = 0; jj < 4; ++jj)
      gld16(src + (jj * 512 + tid) * 8, &Bl[buf][(jj * 512 + w * 64) * 8]);
    if (tid < 64) ncs[buf][tid] = nrm[colslice + t * 64 + tid];
  };

  const int tdiag = rb * 2 - cs * 16;  // in [0,16) only for the diagonal slice

  stage(0, 0);
  for (int t = 0; t < 16; ++t) {
    const int cur = t & 1;
    __syncthreads();                        // Bl[cur] ready
    if (t + 1 < 16) stage(cur ^ 1, t + 1);  // prefetch overlaps compute
    const int cbase = colslice + t * 64;
    f32x4 acc[2][2];
    #pragma unroll
    for (int rf = 0; rf < 2; ++rf) {
      f32x4 z = {0.f, 0.f, 0.f, 0.f};
      acc[rf][0] = z; acc[rf][1] = z;
    }
    #pragma unroll
    for (int kf = 0; kf < 8; ++kf) {
      const int gs = ((kf << 2) | l4) ^ (l15 & 7);
      const s8v b0 = *reinterpret_cast<const s8v*>(&Bl[cur][(wcol + l15) * NK + gs * 8]);
      const s8v b1 = *reinterpret_cast<const s8v*>(&Bl[cur][(wcol + 16 + l15) * NK + gs * 8]);
      #pragma unroll
      for (int rf = 0; rf < 2; ++rf) {
        acc[rf][0] = __builtin_amdgcn_mfma_f32_16x16x32_bf16(A[rf][kf], b0, acc[rf][0], 0, 0, 0);
        acc[rf][1] = __builtin_amdgcn_mfma_f32_16x16x32_bf16(A[rf][kf], b1, acc[rf][1], 0, 0, 0);
      }
    }
    // epilogue: d, exp(-d) -> dn; ballot-ranked passer stores (atomic-free)
    const float nc0 = ncs[cur][wcol + l15];
    const float nc1 = ncs[cur][wcol + 16 + l15];
    const int colg0 = cbase + wcol + l15;
    const int colg1 = colg0 + 16;
    const int gt4 = (cs * 16 + t) * 4;
    auto epi = [&](auto dgc) {
      constexpr bool DG = decltype(dgc)::value;
      #pragma unroll
      for (int rf = 0; rf < 2; ++rf)
        #pragma unroll
        for (int q = 0; q < 4; ++q) {
          const int rowg = rowbase + rf * 16 + l4 * 4 + q;
          float sq0 = fmaf(acc[rf][0][q], -2.0f, nr[rf][q] + nc0);
          float sq1 = fmaf(acc[rf][1][q], -2.0f, nr[rf][q] + nc1);
          if (DG) { sq0 = fmaxf(sq0, 0.0f); sq1 = fmaxf(sq1, 0.0f); }
          const float d0 = __builtin_amdgcn_sqrtf(sq0);
          const float d1 = __builtin_amdgcn_sqrtf(sq1);
          float e0 = __expf(-d0), e1 = __expf(-d1);
          bool p0 = sq0 < tk2[rf][q];
          bool p1 = sq1 < tk2[rf][q];
          if (DG) {
            const bool nd0 = (rowg != colg0), nd1 = (rowg != colg1);
            e0 = nd0 ? e0 : 0.0f;  e1 = nd1 ? e1 : 0.0f;
            p0 = p0 && nd0;  p1 = p1 && nd1;
          }
          dn[rf][q] += e0 + e1;
          const unsigned long long m0 = __ballot(p0);
          const unsigned long long m1 = __ballot(p1);
          if ((m0 | m1) != 0ull) {     // wave-uniform skip
            const int r0 = __popcll(m0 & sub & ltm);  // rank in row-subgroup
            const int r1 = __popcll(m1 & sub & ltm);
            if (p0 && r0 < PSLOT) {
              const unsigned d16 = __half_as_ushort(__float2half(d0));
              pass[rowg * 512 + gt4 + r0] = (d16 << 16) | (unsigned)colg0;
            }
            if (p1 && r1 < PSLOT) {
              const unsigned d16 = __half_as_ushort(__float2half(d1));
              pass[rowg * 512 + gt4 + 2 + r1] = (d16 << 16) | (unsigned)colg1;
            }
          }
        }
    };
    if (t == tdiag || t == tdiag + 1) epi(BoolC<true>{});
    else                              epi(BoolC<false>{});
  }
  // per-row denom partial: shfl over the 16 lanes of a row, LDS-combine waves
  #pragma unroll
  for (int rf = 0; rf < 2; ++rf)
    #pragma unroll
    for (int q = 0; q < 4; ++q) {
      float vs = dn[rf][q];
      vs += __shfl_xor(vs, 1); vs += __shfl_xor(vs, 2);
      vs += __shfl_xor(vs, 4); vs += __shfl_xor(vs, 8);
      if (l15 == 0) atomicAdd(&dpart[(w >> 1) * 32 + rf * 16 + l4 * 4 + q], vs);
    }
  __syncthreads();
  if (tid < 128) dnp[(rb * 128 + tid) * 8 + cs] = dpart[tid];
}

// ----------------------------------------------------------------- k_fin ----
__global__ __launch_bounds__(256) void k_fin(const unsigned* __restrict__ pass,
                                             const float* __restrict__ dnp,
                                             const int* __restrict__ y,
                                             float* __restrict__ out) {
  const int w = threadIdx.x >> 6, l = threadIdx.x & 63;
  const int r = blockIdx.x * 4 + w;
  unsigned kk[8];
  const uint4 pa = *reinterpret_cast<const uint4*>(pass + r * 512 + l * 8);
  const uint4 pb = *reinterpret_cast<const uint4*>(pass + r * 512 + l * 8 + 4);
  kk[0] = pa.x; kk[1] = pa.y; kk[2] = pa.z; kk[3] = pa.w;
  kk[4] = pb.x; kk[5] = pb.y; kk[6] = pb.z; kk[7] = pb.w;
  unsigned myKey = 0xFFFFFFFFu;
  for (int pp = 0; pp < 16; ++pp) {
    unsigned lm = kk[0];
    #pragma unroll
    for (int j = 1; j < 8; ++j) lm = umin32(lm, kk[j]);
    unsigned m = lm;
    m = umin32(m, __shfl_xor(m, 1));  m = umin32(m, __shfl_xor(m, 2));
    m = umin32(m, __shfl_xor(m, 4));  m = umin32(m, __shfl_xor(m, 8));
    m = umin32(m, __shfl_xor(m, 16)); m = umin32(m, __shfl_xor(m, 32));
    const unsigned long long bal = __ballot(lm == m);
    const int owner = (int)__ffsll(bal) - 1;
    if (l == owner) {
      bool f = false;
      #pragma unroll
      for (int j = 0; j < 8; ++j)
        if (!f && kk[j] == m) { kk[j] = 0xFFFFFFFFu; f = true; }
    }
    if (l == pp) myKey = m;  // lanes 0..15 collect the 16 nearest keys
  }
  float den = 0.0f;
  #pragma unroll
  for (int cs = 0; cs < 8; ++cs) den += dnp[r * 8 + cs];
  const float logden = __logf(den);
  float contrib = 0.0f, cmf = 0.0f;
  if (l < 16 && myKey != 0xFFFFFFFFu) {
    const int col = (int)(myKey & 0x1FFFu);
    const float dd = __half2float(__ushort_as_half((unsigned short)(myKey >> 16)));
    if (y[col] == y[r]) { contrib = -dd - logden; cmf = 1.0f; }
  }
  contrib += __shfl_xor(contrib, 1);  contrib += __shfl_xor(contrib, 2);
  contrib += __shfl_xor(contrib, 4);  contrib += __shfl_xor(contrib, 8);
  contrib += __shfl_xor(contrib, 16); contrib += __shfl_xor(contrib, 32);
  cmf += __shfl_xor(cmf, 1);  cmf += __shfl_xor(cmf, 2);
  cmf += __shfl_xor(cmf, 4);  cmf += __shfl_xor(cmf, 8);
  cmf += __shfl_xor(cmf, 16); cmf += __shfl_xor(cmf, 32);
  if (l == 0 && cmf > 0.0f)
    atomicAdd(out, (contrib / cmf) * (-1.0f / 8192.0f));
}

// ---------------------------------------------------------------------------
extern "C" void kernel_launch(void* const* d_in, const int* in_sizes, int n_in,
                              void* d_out, int out_size, void* d_ws, size_t ws_size,
                              hipStream_t stream) {
  const float* x = (const float*)d_in[0];
  const int* y = (const int*)d_in[1];
  float* out = (float*)d_out;
  char* ws = (char*)d_ws;

  float*          dnp  = (float*)(ws + OFF_DNP);
  float*          nrm  = (float*)(ws + OFF_NRM);
  unsigned*       tauk = (unsigned*)(ws + OFF_TAU);
  unsigned short* xb   = (unsigned short*)(ws + OFF_XB);
  unsigned short* samp = (unsigned short*)(ws + OFF_SAMP);
  unsigned*       pass = (unsigned*)(ws + OFF_PASS);  // overlaps samp (after k_tau)

  k_prep<<<2048, 256, 0, stream>>>(x, xb, nrm);
  k_samp<<<512,  512, 0, stream>>>(xb, nrm, samp);
  k_tau <<<2048, 256, 0, stream>>>(samp, tauk);
  hipMemsetAsync(pass, 0xFF, PASS_BYTES, stream);   // empty-key fill (per replay)
  hipMemsetAsync(d_out, 0, sizeof(float), stream);
  k_main<<<512,  512, 0, stream>>>(xb, nrm, tauk, dnp, pass);
  k_fin <<<2048, 256, 0, stream>>>(pass, dnp, y, out);
}